// Round 12
// baseline (171.327 us; speedup 1.0000x reference)
//
#include <hip/hip_runtime.h>
#include <hip/hip_cooperative_groups.h>
#include <stdint.h>

namespace cg = cooperative_groups;

#define EMBED 1024
#define BATCH 256
#define NTERM 11         // Taylor n=0..10; |q*k/32| <= ~0.25 -> remainder < 1e-13

#define BM 32
#define BN 128
#define BK 64
#define LPAD (BK + 8)    // 72 bf16 = 144B row stride; b128 frag reads 2-way banked = free

typedef float f4 __attribute__((ext_vector_type(4)));
typedef short bf16x8 __attribute__((ext_vector_type(8)));   // 8 bf16 = 4 VGPRs

__device__ const float g_fact[NTERM] = {
    1.f, 1.f, 2.f, 6.f, 24.f, 120.f, 720.f, 5040.f, 40320.f, 362880.f, 3628800.f
};

// pack two fp32 -> packed bf16 pair (near-RNE)
__device__ __forceinline__ int packbf(float f0, float f1) {
    unsigned int u0 = __float_as_uint(f0) + 0x8000u;
    unsigned int u1 = __float_as_uint(f1) + 0x8000u;
    return (int)((u0 >> 16) | (u1 & 0xffff0000u));
}
__device__ __forceinline__ bf16x8 cvt8(f4 lo, f4 hi) {
    union { int i[4]; bf16x8 v; } u;
    u.i[0] = packbf(lo.x, lo.y);
    u.i[1] = packbf(lo.z, lo.w);
    u.i[2] = packbf(hi.x, hi.y);
    u.i[3] = packbf(hi.z, hi.w);
    return u.v;
}

// Single cooperative kernel: phase 1 = QKV GEMM (192 tiles of 32x128 over 256
// blocks), grid.sync(), phase 2 = moment-collapsed softmax (block b -> row b).
// Tests the launch-overhead theory: R7-R11 showed gemm wall time invariant to
// every internal structure change -> suspect per-launch cost, not kernel work.
__global__ __launch_bounds__(256) void fused_attn(
    const float* __restrict__ x,
    const float* __restrict__ Wq,
    const float* __restrict__ Wk,
    const float* __restrict__ Wv,
    float* __restrict__ qkv,
    float* __restrict__ out)
{
    const int bid = blockIdx.x;
    const int tid = threadIdx.x;

    __shared__ __align__(16) short As[BM * LPAD];   // 4.6 KB
    __shared__ __align__(16) short Bs[BN * LPAD];   // 18.4 KB

    // ---------------- Phase 1: GEMM (blocks 0..191) ----------------
    if (bid < 192) {
        const int z    = bid >> 6;                 // 0..2
        const int rem  = bid & 63;
        const int row0 = (rem >> 3) * BM;          // 8 row-tiles
        const int col0 = (rem & 7) * BN;           // 8 col-tiles
        const float* __restrict__ W = (z == 0) ? Wq : (z == 1) ? Wk : Wv;
        float* __restrict__ C = qkv + (size_t)z * BATCH * EMBED;

        // staging: A row t>>3, k [(t&7)*8,+8); B row t>>1, k [(t&1)*32,+32)
        const int ar = tid >> 3, ak = (tid & 7) * 8;
        const int br = tid >> 1, bk = (tid & 1) * 32;
        const float* __restrict__ ag = x + (size_t)(row0 + ar) * EMBED + ak;
        const float* __restrict__ bg = W + (size_t)(col0 + br) * EMBED + bk;

        // compute: 4 waves in 2x2; wave w -> rows [16*(w&1),+16), cols [64*(w>>1),+64)
        const int lane   = tid & 63;
        const int wv     = tid >> 6;
        const int lane16 = lane & 15;
        const int quad   = lane >> 4;
        const int wrow   = (wv & 1) * 16;
        const int wcol   = (wv >> 1) * 64;

        const short* __restrict__ afp = As + (wrow + lane16) * LPAD + quad * 8;
        const short* __restrict__ bfp = Bs + (wcol + lane16) * LPAD + quad * 8;

        f4 acc0 = {0.f, 0.f, 0.f, 0.f}, acc1 = acc0, acc2 = acc0, acc3 = acc0;

        f4 pa[2], pb[8];
        #pragma unroll
        for (int i = 0; i < 2; ++i) pa[i] = *(const f4*)(ag + 4 * i);
        #pragma unroll
        for (int i = 0; i < 8; ++i) pb[i] = *(const f4*)(bg + 4 * i);

        for (int kt = 0; kt < EMBED; kt += BK) {
            *(bf16x8*)&As[ar * LPAD + ak] = cvt8(pa[0], pa[1]);
            #pragma unroll
            for (int j = 0; j < 4; ++j)
                *(bf16x8*)&Bs[br * LPAD + bk + 8 * j] = cvt8(pb[2 * j], pb[2 * j + 1]);
            __syncthreads();

            if (kt + BK < EMBED) {
                #pragma unroll
                for (int i = 0; i < 2; ++i) pa[i] = *(const f4*)(ag + kt + BK + 4 * i);
                #pragma unroll
                for (int i = 0; i < 8; ++i) pb[i] = *(const f4*)(bg + kt + BK + 4 * i);
            }

            #pragma unroll
            for (int st = 0; st < 2; ++st) {
                bf16x8 af = *(const bf16x8*)(afp + st * 32);
                bf16x8 b0 = *(const bf16x8*)(bfp + st * 32);
                bf16x8 b1 = *(const bf16x8*)(bfp + 16 * LPAD + st * 32);
                bf16x8 b2 = *(const bf16x8*)(bfp + 32 * LPAD + st * 32);
                bf16x8 b3 = *(const bf16x8*)(bfp + 48 * LPAD + st * 32);
                acc0 = __builtin_amdgcn_mfma_f32_16x16x32_bf16(af, b0, acc0, 0, 0, 0);
                acc1 = __builtin_amdgcn_mfma_f32_16x16x32_bf16(af, b1, acc1, 0, 0, 0);
                acc2 = __builtin_amdgcn_mfma_f32_16x16x32_bf16(af, b2, acc2, 0, 0, 0);
                acc3 = __builtin_amdgcn_mfma_f32_16x16x32_bf16(af, b3, acc3, 0, 0, 0);
            }
            __syncthreads();
        }

        // C/D layout (m89-verified): col = lane&15, row = quad*4 + reg
        const int crow = row0 + wrow + quad * 4;
        float* __restrict__ cp = C + (size_t)crow * EMBED + col0 + wcol + lane16;
        #pragma unroll
        for (int r = 0; r < 4; ++r) {
            cp[(size_t)r * EMBED +  0] = acc0[r];
            cp[(size_t)r * EMBED + 16] = acc1[r];
            cp[(size_t)r * EMBED + 32] = acc2[r];
            cp[(size_t)r * EMBED + 48] = acc3[r];
        }
    }

    // device-scope visibility of qkv across XCDs, then grid-wide barrier
    __threadfence();
    cg::this_grid().sync();

    // ---------------- Phase 2: moments + Horner (block b -> row b) ----------------
    const int b = bid;
    const float* __restrict__ Q = qkv;
    const float* __restrict__ K = qkv + (size_t)BATCH * EMBED;
    const float* __restrict__ V = qkv + (size_t)2 * BATCH * EMBED;

    f4 k4 = *(const f4*)&K[(size_t)b * EMBED + tid * 4];
    f4 v4 = *(const f4*)&V[(size_t)b * EMBED + tid * 4];

    float m1[NTERM], mv[NTERM];
    #pragma unroll
    for (int n = 0; n < NTERM; ++n) { m1[n] = 0.f; mv[n] = 0.f; }

    #pragma unroll
    for (int r = 0; r < 4; ++r) {
        float kv = k4[r], vv = v4[r];
        float p = 1.f;
        #pragma unroll
        for (int n = 0; n < NTERM; ++n) {
            m1[n] += p;
            mv[n] = __builtin_fmaf(p, vv, mv[n]);
            p *= kv;
        }
    }

    #pragma unroll
    for (int n = 0; n < NTERM; ++n) {
        #pragma unroll
        for (int off = 32; off >= 1; off >>= 1) {
            m1[n] += __shfl_xor(m1[n], off);
            mv[n] += __shfl_xor(mv[n], off);
        }
    }

    __shared__ float part[4][2 * NTERM];
    const int wave = tid >> 6;
    const int lane = tid & 63;
    if (lane == 0) {
        #pragma unroll
        for (int n = 0; n < NTERM; ++n) {
            part[wave][n]         = m1[n];
            part[wave][NTERM + n] = mv[n];
        }
    }
    __syncthreads();

    __shared__ float coef[2 * NTERM];
    if (tid < 2 * NTERM) {
        float s = part[0][tid] + part[1][tid] + part[2][tid] + part[3][tid];
        int n = (tid < NTERM) ? tid : (tid - NTERM);
        coef[tid] = s / g_fact[n];
    }
    __syncthreads();

    float c1[NTERM], cv[NTERM];
    #pragma unroll
    for (int n = 0; n < NTERM; ++n) { c1[n] = coef[n]; cv[n] = coef[NTERM + n]; }

    f4 q4 = *(const f4*)&Q[(size_t)b * EMBED + tid * 4];
    f4 res;
    #pragma unroll
    for (int r = 0; r < 4; ++r) {
        float t = q4[r] * 0.03125f;   // 1/sqrt(1024) = 1/32 exactly
        float den = c1[NTERM - 1];
        float num = cv[NTERM - 1];
        #pragma unroll
        for (int n = NTERM - 2; n >= 0; --n) {
            den = __builtin_fmaf(den, t, c1[n]);
            num = __builtin_fmaf(num, t, cv[n]);
        }
        res[r] = num / den;
    }

    *(f4*)&out[(size_t)b * EMBED + tid * 4] = res;
}

extern "C" void kernel_launch(void* const* d_in, const int* in_sizes, int n_in,
                              void* d_out, int out_size, void* d_ws, size_t ws_size,
                              hipStream_t stream) {
    const float* x  = (const float*)d_in[0];
    const float* Wq = (const float*)d_in[1];
    const float* Wk = (const float*)d_in[2];
    const float* Wv = (const float*)d_in[3];
    float* qkv  = (float*)d_ws;                   // 3*256*1024 fp32 = 3 MB scratch
    float* outp = (float*)d_out;

    void* args[] = { (void*)&x, (void*)&Wq, (void*)&Wk, (void*)&Wv,
                     (void*)&qkv, (void*)&outp };
    hipLaunchCooperativeKernel((const void*)fused_attn,
                               dim3(BATCH), dim3(256), args, 0, stream);
}

// Round 13
// 87.482 us; speedup vs baseline: 1.9584x; 1.9584x over previous
//
#include <hip/hip_runtime.h>
#include <stdint.h>

#define EMBED 1024
#define BATCH 256
#define NTERM 11         // Taylor n=0..10; |q*k/32| <= ~0.25 -> remainder < 1e-13

#define BM 16
#define BN 64
#define BK 64
#define LPAD (BK + 8)    // 72 bf16 = 144B row stride; b128 frag reads 2-way banked = free

typedef float f4 __attribute__((ext_vector_type(4)));
typedef short bf16x8 __attribute__((ext_vector_type(8)));   // 8 bf16 = 4 VGPRs

__device__ const float g_fact[NTERM] = {
    1.f, 1.f, 2.f, 6.f, 24.f, 120.f, 720.f, 5040.f, 40320.f, 362880.f, 3628800.f
};

// pack two fp32 -> packed bf16 pair (near-RNE)
__device__ __forceinline__ int packbf(float f0, float f1) {
    unsigned int u0 = __float_as_uint(f0) + 0x8000u;
    unsigned int u1 = __float_as_uint(f1) + 0x8000u;
    return (int)((u0 >> 16) | (u1 & 0xffff0000u));
}
__device__ __forceinline__ bf16x8 cvt8(f4 lo, f4 hi) {
    union { int i[4]; bf16x8 v; } u;
    u.i[0] = packbf(lo.x, lo.y);
    u.i[1] = packbf(lo.z, lo.w);
    u.i[2] = packbf(hi.x, hi.y);
    u.i[3] = packbf(hi.z, hi.w);
    return u.v;
}

// R9 structure + XCD-aware swizzle. 1D grid of 768 blocks; assuming round-robin
// block->XCD dispatch (b%8), remap so all 16 row-blocks sharing one (col,z)
// W-slab (256 KB) land on ONE XCD: W enters each XCD's L2 once instead of 8x.
// Per XCD: 6 slabs (1.5 MB) + x (1 MB) < 4 MB L2.
__global__ __launch_bounds__(128) void gemm_qkv_mfma(
    const float* __restrict__ x,
    const float* __restrict__ Wq,
    const float* __restrict__ Wk,
    const float* __restrict__ Wv,
    float* __restrict__ qkv)
{
    // swizzle: g -> (xcd = g&7, slot = g>>3); pair p = xcd*6 + slot/16 in [0,48)
    // encodes (z = p/16, col-tile = p%16); row-tile = slot&15.
    const int g    = blockIdx.x;
    const int xcd  = g & 7;
    const int slot = g >> 3;
    const int p    = xcd * 6 + (slot >> 4);
    const int z    = p >> 4;
    const int row0 = (slot & 15) * BM;
    const int col0 = (p & 15) * BN;

    const float* __restrict__ W = (z == 0) ? Wq : (z == 1) ? Wk : Wv;
    float* __restrict__ C = qkv + (size_t)z * BATCH * EMBED;

    const int tid = threadIdx.x;

    __shared__ __align__(16) short As[BM * LPAD];   // 2.3 KB
    __shared__ __align__(16) short Bs[BN * LPAD];   // 9.2 KB

    // staging: thread t -> row t>>3 (16 rows), k-cols [(t&7)*8, +8)
    const int sr = tid >> 3;            // 0..15
    const int sk = (tid & 7) * 8;       // 0..56

    const float* __restrict__ ag = x + (size_t)(row0 + sr) * EMBED + sk;
    const float* __restrict__ bg = W + (size_t)(col0 + sr) * EMBED + sk;

    // compute assignments
    const int lane   = tid & 63;
    const int wv     = tid >> 6;        // 0..1
    const int lane16 = lane & 15;
    const int quad   = lane >> 4;
    const int wcol   = wv * 32;

    const short* __restrict__ afp  = As + lane16 * LPAD + quad * 8;
    const short* __restrict__ bfp0 = Bs + (wcol + lane16) * LPAD + quad * 8;
    const short* __restrict__ bfp1 = Bs + (wcol + 16 + lane16) * LPAD + quad * 8;

    f4 acc0 = {0.f, 0.f, 0.f, 0.f}, acc1 = acc0;

    // prefetch tile 0: A 8 floats, B 4 row-passes x 8 floats
    f4 pa0 = *(const f4*)(ag), pa1 = *(const f4*)(ag + 4);
    f4 pb[8];
    #pragma unroll
    for (int i = 0; i < 4; ++i) {
        pb[2 * i]     = *(const f4*)(bg + (size_t)16 * i * EMBED);
        pb[2 * i + 1] = *(const f4*)(bg + (size_t)16 * i * EMBED + 4);
    }

    for (int kt = 0; kt < EMBED; kt += BK) {
        *(bf16x8*)&As[sr * LPAD + sk] = cvt8(pa0, pa1);
        #pragma unroll
        for (int i = 0; i < 4; ++i)
            *(bf16x8*)&Bs[(sr + 16 * i) * LPAD + sk] = cvt8(pb[2 * i], pb[2 * i + 1]);
        __syncthreads();

        if (kt + BK < EMBED) {
            pa0 = *(const f4*)(ag + kt + BK);
            pa1 = *(const f4*)(ag + kt + BK + 4);
            #pragma unroll
            for (int i = 0; i < 4; ++i) {
                pb[2 * i]     = *(const f4*)(bg + (size_t)16 * i * EMBED + kt + BK);
                pb[2 * i + 1] = *(const f4*)(bg + (size_t)16 * i * EMBED + kt + BK + 4);
            }
        }

        #pragma unroll
        for (int s = 0; s < 2; ++s) {
            bf16x8 af  = *(const bf16x8*)(afp  + s * 32);
            bf16x8 bf0 = *(const bf16x8*)(bfp0 + s * 32);
            bf16x8 bf1 = *(const bf16x8*)(bfp1 + s * 32);
            acc0 = __builtin_amdgcn_mfma_f32_16x16x32_bf16(af, bf0, acc0, 0, 0, 0);
            acc1 = __builtin_amdgcn_mfma_f32_16x16x32_bf16(af, bf1, acc1, 0, 0, 0);
        }
        __syncthreads();
    }

    // C/D layout (m89-verified): col = lane&15, row = quad*4 + reg
    const int crow = row0 + quad * 4;
    float* __restrict__ cp = C + (size_t)crow * EMBED + col0 + wcol + lane16;
    #pragma unroll
    for (int r = 0; r < 4; ++r) {
        cp[(size_t)r * EMBED +  0] = acc0[r];
        cp[(size_t)r * EMBED + 16] = acc1[r];
    }
}

// One block per batch row. out[b,i] = P(t)/Q(t), t=q[b,i]/32,
// P = sum_n (Mv_n/n!) t^n, Q = sum_n (M1_n/n!) t^n,
// Mv_n = sum_j k_j^n v_j, M1_n = sum_j k_j^n  (exact collapse of rank-1 softmax).
__global__ __launch_bounds__(256) void attn_moments(
    const float* __restrict__ qkv,
    float* __restrict__ out)
{
    const int b   = blockIdx.x;
    const int tid = threadIdx.x;
    const float* __restrict__ Q = qkv;
    const float* __restrict__ K = qkv + (size_t)BATCH * EMBED;
    const float* __restrict__ V = qkv + (size_t)2 * BATCH * EMBED;

    f4 k4 = *(const f4*)&K[(size_t)b * EMBED + tid * 4];
    f4 v4 = *(const f4*)&V[(size_t)b * EMBED + tid * 4];

    float m1[NTERM], mv[NTERM];
    #pragma unroll
    for (int n = 0; n < NTERM; ++n) { m1[n] = 0.f; mv[n] = 0.f; }

    #pragma unroll
    for (int r = 0; r < 4; ++r) {
        float kv = k4[r], vv = v4[r];
        float p = 1.f;
        #pragma unroll
        for (int n = 0; n < NTERM; ++n) {
            m1[n] += p;
            mv[n] = __builtin_fmaf(p, vv, mv[n]);
            p *= kv;
        }
    }

    #pragma unroll
    for (int n = 0; n < NTERM; ++n) {
        #pragma unroll
        for (int off = 32; off >= 1; off >>= 1) {
            m1[n] += __shfl_xor(m1[n], off);
            mv[n] += __shfl_xor(mv[n], off);
        }
    }

    __shared__ float part[4][2 * NTERM];
    const int wave = tid >> 6;
    const int lane = tid & 63;
    if (lane == 0) {
        #pragma unroll
        for (int n = 0; n < NTERM; ++n) {
            part[wave][n]         = m1[n];
            part[wave][NTERM + n] = mv[n];
        }
    }
    __syncthreads();

    __shared__ float coef[2 * NTERM];
    if (tid < 2 * NTERM) {
        float s = part[0][tid] + part[1][tid] + part[2][tid] + part[3][tid];
        int n = (tid < NTERM) ? tid : (tid - NTERM);
        coef[tid] = s / g_fact[n];
    }
    __syncthreads();

    float c1[NTERM], cv[NTERM];
    #pragma unroll
    for (int n = 0; n < NTERM; ++n) { c1[n] = coef[n]; cv[n] = coef[NTERM + n]; }

    f4 q4 = *(const f4*)&Q[(size_t)b * EMBED + tid * 4];
    f4 res;
    #pragma unroll
    for (int r = 0; r < 4; ++r) {
        float t = q4[r] * 0.03125f;   // 1/sqrt(1024) = 1/32 exactly
        float den = c1[NTERM - 1];
        float num = cv[NTERM - 1];
        #pragma unroll
        for (int n = NTERM - 2; n >= 0; --n) {
            den = __builtin_fmaf(den, t, c1[n]);
            num = __builtin_fmaf(num, t, cv[n]);
        }
        res[r] = num / den;
    }

    *(f4*)&out[(size_t)b * EMBED + tid * 4] = res;
}

extern "C" void kernel_launch(void* const* d_in, const int* in_sizes, int n_in,
                              void* d_out, int out_size, void* d_ws, size_t ws_size,
                              hipStream_t stream) {
    const float* x  = (const float*)d_in[0];
    const float* Wq = (const float*)d_in[1];
    const float* Wk = (const float*)d_in[2];
    const float* Wv = (const float*)d_in[3];
    float* qkv  = (float*)d_ws;                   // 3*256*1024 fp32 = 3 MB scratch
    float* outp = (float*)d_out;

    gemm_qkv_mfma<<<768, 128, 0, stream>>>(x, Wq, Wk, Wv, qkv);   // 1D grid, XCD swizzle inside
    attn_moments<<<BATCH, 256, 0, stream>>>(qkv, outp);
}

// Round 14
// 83.147 us; speedup vs baseline: 2.0605x; 1.0521x over previous
//
#include <hip/hip_runtime.h>
#include <stdint.h>

#define EMBED 1024
#define BATCH 256
#define NTERM 11         // Taylor n=0..10; |q*k/32| <= ~0.25 -> remainder < 1e-13

#define BM 16
#define BN 64
#define BK 64
#define LPAD (BK + 8)    // 72 bf16 = 144B row stride; b128 frag reads 2-way banked = free (m136)

typedef float f4 __attribute__((ext_vector_type(4)));
typedef short bf16x8 __attribute__((ext_vector_type(8)));   // 8 bf16 = 4 VGPRs

__device__ const float g_fact[NTERM] = {
    1.f, 1.f, 2.f, 6.f, 24.f, 120.f, 720.f, 5040.f, 40320.f, 362880.f, 3628800.f
};

// pack two fp32 -> packed bf16 pair (near-RNE)
__device__ __forceinline__ int packbf(float f0, float f1) {
    unsigned int u0 = __float_as_uint(f0) + 0x8000u;
    unsigned int u1 = __float_as_uint(f1) + 0x8000u;
    return (int)((u0 >> 16) | (u1 & 0xffff0000u));
}
__device__ __forceinline__ bf16x8 cvt8(f4 lo, f4 hi) {
    union { int i[4]; bf16x8 v; } u;
    u.i[0] = packbf(lo.x, lo.y);
    u.i[1] = packbf(lo.z, lo.w);
    u.i[2] = packbf(hi.x, hi.y);
    u.i[3] = packbf(hi.z, hi.w);
    return u.v;
}

// R9 kernel (session-best, 83.39 us total): BK=64, reg-prefetch, bf16 LDS
// staging, ds_read_b128 frags, 16x16x32 MFMA, 768 blocks = 3/CU.
// NOTE (session finding): total time is floored at ~83 us by the harness's
// 256 MB ws poison fill (41 us) + the subsequent dirty-L3 drain (~39 us)
// that runs concurrently with and starves these kernels; kernel work below
// ~39 us is hidden under the drain, which is why R7-R13's structural
// changes (occupancy, tiles, split-K, fusion, XCD swizzle) were all neutral.
__global__ __launch_bounds__(128) void gemm_qkv_mfma(
    const float* __restrict__ x,
    const float* __restrict__ Wq,
    const float* __restrict__ Wk,
    const float* __restrict__ Wv,
    float* __restrict__ qkv)
{
    const int z = blockIdx.z;
    const float* __restrict__ W = (z == 0) ? Wq : (z == 1) ? Wk : Wv;
    float* __restrict__ C = qkv + (size_t)z * BATCH * EMBED;

    const int row0 = blockIdx.x * BM;
    const int col0 = blockIdx.y * BN;
    const int tid  = threadIdx.x;

    __shared__ __align__(16) short As[BM * LPAD];   // 2.3 KB
    __shared__ __align__(16) short Bs[BN * LPAD];   // 9.2 KB

    // staging: thread t -> row t>>3 (16 rows), k-cols [(t&7)*8, +8)
    const int sr = tid >> 3;            // 0..15
    const int sk = (tid & 7) * 8;       // 0..56

    const float* __restrict__ ag = x + (size_t)(row0 + sr) * EMBED + sk;
    const float* __restrict__ bg = W + (size_t)(col0 + sr) * EMBED + sk;

    // compute assignments
    const int lane   = tid & 63;
    const int wv     = tid >> 6;        // 0..1
    const int lane16 = lane & 15;
    const int quad   = lane >> 4;
    const int wcol   = wv * 32;

    const short* __restrict__ afp  = As + lane16 * LPAD + quad * 8;
    const short* __restrict__ bfp0 = Bs + (wcol + lane16) * LPAD + quad * 8;
    const short* __restrict__ bfp1 = Bs + (wcol + 16 + lane16) * LPAD + quad * 8;

    f4 acc0 = {0.f, 0.f, 0.f, 0.f}, acc1 = acc0;

    // prefetch tile 0 into registers: A 1x8 floats, B 4 row-passes x 8 floats
    f4 pa0 = *(const f4*)(ag), pa1 = *(const f4*)(ag + 4);
    f4 pb[8];
    #pragma unroll
    for (int i = 0; i < 4; ++i) {
        pb[2 * i]     = *(const f4*)(bg + (size_t)16 * i * EMBED);
        pb[2 * i + 1] = *(const f4*)(bg + (size_t)16 * i * EMBED + 4);
    }

    for (int kt = 0; kt < EMBED; kt += BK) {
        // regs -> bf16 -> LDS
        *(bf16x8*)&As[sr * LPAD + sk] = cvt8(pa0, pa1);
        #pragma unroll
        for (int i = 0; i < 4; ++i)
            *(bf16x8*)&Bs[(sr + 16 * i) * LPAD + sk] = cvt8(pb[2 * i], pb[2 * i + 1]);
        __syncthreads();

        // prefetch next tile while computing this one
        if (kt + BK < EMBED) {
            pa0 = *(const f4*)(ag + kt + BK);
            pa1 = *(const f4*)(ag + kt + BK + 4);
            #pragma unroll
            for (int i = 0; i < 4; ++i) {
                pb[2 * i]     = *(const f4*)(bg + (size_t)16 * i * EMBED + kt + BK);
                pb[2 * i + 1] = *(const f4*)(bg + (size_t)16 * i * EMBED + kt + BK + 4);
            }
        }

        #pragma unroll
        for (int s = 0; s < 2; ++s) {
            bf16x8 af  = *(const bf16x8*)(afp  + s * 32);
            bf16x8 bf0 = *(const bf16x8*)(bfp0 + s * 32);
            bf16x8 bf1 = *(const bf16x8*)(bfp1 + s * 32);
            acc0 = __builtin_amdgcn_mfma_f32_16x16x32_bf16(af, bf0, acc0, 0, 0, 0);
            acc1 = __builtin_amdgcn_mfma_f32_16x16x32_bf16(af, bf1, acc1, 0, 0, 0);
        }
        __syncthreads();
    }

    // C/D layout (m89-verified): col = lane&15, row = quad*4 + reg
    const int crow = row0 + quad * 4;
    float* __restrict__ cp = C + (size_t)crow * EMBED + col0 + wcol + lane16;
    #pragma unroll
    for (int r = 0; r < 4; ++r) {
        cp[(size_t)r * EMBED +  0] = acc0[r];
        cp[(size_t)r * EMBED + 16] = acc1[r];
    }
}

// One block per batch row. out[b,i] = P(t)/Q(t), t=q[b,i]/32,
// P = sum_n (Mv_n/n!) t^n, Q = sum_n (M1_n/n!) t^n,
// Mv_n = sum_j k_j^n v_j, M1_n = sum_j k_j^n  (exact collapse of rank-1 softmax).
__global__ __launch_bounds__(256) void attn_moments(
    const float* __restrict__ qkv,
    float* __restrict__ out)
{
    const int b   = blockIdx.x;
    const int tid = threadIdx.x;
    const float* __restrict__ Q = qkv;
    const float* __restrict__ K = qkv + (size_t)BATCH * EMBED;
    const float* __restrict__ V = qkv + (size_t)2 * BATCH * EMBED;

    f4 k4 = *(const f4*)&K[(size_t)b * EMBED + tid * 4];
    f4 v4 = *(const f4*)&V[(size_t)b * EMBED + tid * 4];

    float m1[NTERM], mv[NTERM];
    #pragma unroll
    for (int n = 0; n < NTERM; ++n) { m1[n] = 0.f; mv[n] = 0.f; }

    #pragma unroll
    for (int r = 0; r < 4; ++r) {
        float kv = k4[r], vv = v4[r];
        float p = 1.f;
        #pragma unroll
        for (int n = 0; n < NTERM; ++n) {
            m1[n] += p;
            mv[n] = __builtin_fmaf(p, vv, mv[n]);
            p *= kv;
        }
    }

    #pragma unroll
    for (int n = 0; n < NTERM; ++n) {
        #pragma unroll
        for (int off = 32; off >= 1; off >>= 1) {
            m1[n] += __shfl_xor(m1[n], off);
            mv[n] += __shfl_xor(mv[n], off);
        }
    }

    __shared__ float part[4][2 * NTERM];
    const int wave = tid >> 6;
    const int lane = tid & 63;
    if (lane == 0) {
        #pragma unroll
        for (int n = 0; n < NTERM; ++n) {
            part[wave][n]         = m1[n];
            part[wave][NTERM + n] = mv[n];
        }
    }
    __syncthreads();

    __shared__ float coef[2 * NTERM];
    if (tid < 2 * NTERM) {
        float s = part[0][tid] + part[1][tid] + part[2][tid] + part[3][tid];
        int n = (tid < NTERM) ? tid : (tid - NTERM);
        coef[tid] = s / g_fact[n];
    }
    __syncthreads();

    float c1[NTERM], cv[NTERM];
    #pragma unroll
    for (int n = 0; n < NTERM; ++n) { c1[n] = coef[n]; cv[n] = coef[NTERM + n]; }

    f4 q4 = *(const f4*)&Q[(size_t)b * EMBED + tid * 4];
    f4 res;
    #pragma unroll
    for (int r = 0; r < 4; ++r) {
        float t = q4[r] * 0.03125f;   // 1/sqrt(1024) = 1/32 exactly
        float den = c1[NTERM - 1];
        float num = cv[NTERM - 1];
        #pragma unroll
        for (int n = NTERM - 2; n >= 0; --n) {
            den = __builtin_fmaf(den, t, c1[n]);
            num = __builtin_fmaf(num, t, cv[n]);
        }
        res[r] = num / den;
    }

    *(f4*)&out[(size_t)b * EMBED + tid * 4] = res;
}

extern "C" void kernel_launch(void* const* d_in, const int* in_sizes, int n_in,
                              void* d_out, int out_size, void* d_ws, size_t ws_size,
                              hipStream_t stream) {
    const float* x  = (const float*)d_in[0];
    const float* Wq = (const float*)d_in[1];
    const float* Wk = (const float*)d_in[2];
    const float* Wv = (const float*)d_in[3];
    float* qkv  = (float*)d_ws;                   // 3*256*1024 fp32 = 3 MB scratch
    float* outp = (float*)d_out;

    dim3 g1(BATCH / BM, EMBED / BN, 3);           // 16 x 16 x 3 = 768 blocks = 3/CU exact
    gemm_qkv_mfma<<<g1, 128, 0, stream>>>(x, Wq, Wk, Wv, qkv);
    attn_moments<<<BATCH, 256, 0, stream>>>(qkv, outp);
}